// Round 1
// baseline (459.087 us; speedup 1.0000x reference)
//
#include <hip/hip_runtime.h>
#include <math.h>

#define DD 384
#define HD 1024
#define CD 256
#define NS (2*DD-1)   // 765 shifts
#define NITER 4
#define NROWS 256     // B*T = 2*128
#define TEMPER_F 10.0f
#define EPSF 1e-6f

// One block per (b,t) row. 256 threads.
__global__ __launch_bounds__(256) void fused_kernel(
    const float* __restrict__ x, const float* __restrict__ y,
    const float* __restrict__ Wenc, const float* __restrict__ benc,
    const float* __restrict__ Wdec, const float* __restrict__ bdec,
    float* __restrict__ out_xdis, float* __restrict__ loss_acc)
{
    const int row = blockIdx.x;
    const int tid = threadIdx.x;

    __shared__ float xr[DD], yr[DD], xa[DD], xe[DD];
    __shared__ float red[256];
    __shared__ int   redi[256];
    __shared__ float sv[HD];
    __shared__ int   si[HD];
    __shared__ float s_qn, s_dn, s_mx, s_sum;
    __shared__ int   s_theta;

    const float* xrow = x + row * DD;
    const float* yrow = y + row * DD;
    for (int i = tid; i < DD; i += 256) { xr[i] = xrow[i]; yr[i] = yrow[i]; }
    __syncthreads();

    // ---- qn = ||y_row|| ----
    float p = 0.f;
    for (int i = tid; i < DD; i += 256) p += yr[i] * yr[i];
    red[tid] = p; __syncthreads();
    for (int off = 128; off > 0; off >>= 1) {
        if (tid < off) red[tid] += red[tid + off];
        __syncthreads();
    }
    if (tid == 0) s_qn = sqrtf(red[0]);
    __syncthreads();
    const float qn = s_qn;

    // ---- sim(s) for 765 shifts; argmax with first-max tie-break ----
    // kpt[s][j] = x[s + j - (D-1)] when in range else 0
    float bv = -INFINITY; int bs = 0;
    for (int s = tid; s < NS; s += 256) {
        int lo = s - (DD - 1); if (lo < 0) lo = 0;
        int hi = s + 1;        if (hi > DD) hi = DD;
        const int off = (DD - 1) - s;       // y index = idx + off
        float dot = 0.f, nrm = 0.f;
        for (int idx = lo; idx < hi; ++idx) {
            float xv = xr[idx];
            dot += xv * yr[idx + off];
            nrm += xv * xv;
        }
        float sim = dot / (qn * sqrtf(nrm) + EPSF);
        if (sim > bv) { bv = sim; bs = s; }   // s ascending -> keeps first max
    }
    red[tid] = bv; redi[tid] = bs; __syncthreads();
    for (int off = 128; off > 0; off >>= 1) {
        if (tid < off) {
            float v2 = red[tid + off]; int i2 = redi[tid + off];
            if (v2 > red[tid] || (v2 == red[tid] && i2 < redi[tid])) {
                red[tid] = v2; redi[tid] = i2;
            }
        }
        __syncthreads();
    }
    if (tid == 0) s_theta = redi[0];
    __syncthreads();
    const int theta = s_theta;
    const int sh = theta - (DD - 1);   // x_opt[j] = xr[j + sh]

    // ---- dn = ||x_opt|| * qn + EPS ----
    p = 0.f;
    for (int d = tid; d < DD; d += 256) {
        int src = d + sh;
        if (src >= 0 && src < DD) { float v = xr[src]; p += v * v; }
    }
    red[tid] = p; __syncthreads();
    for (int off = 128; off > 0; off >>= 1) {
        if (tid < off) red[tid] += red[tid + off];
        __syncthreads();
    }
    if (tid == 0) s_dn = sqrtf(red[0]) * qn + EPSF;
    __syncthreads();
    const float dn = s_dn;

    // ---- attn = softmax((x_opt * y / dn) / TEMPER); x_attn = x_opt * attn ----
    float lm = -INFINITY;
    for (int d = tid; d < DD; d += 256) {
        int src = d + sh;
        float xo = (src >= 0 && src < DD) ? xr[src] : 0.f;
        float z = (xo * yr[d] / dn) / TEMPER_F;
        xa[d] = z;
        if (z > lm) lm = z;
    }
    red[tid] = lm; __syncthreads();
    for (int off = 128; off > 0; off >>= 1) {
        if (tid < off) { float v2 = red[tid + off]; if (v2 > red[tid]) red[tid] = v2; }
        __syncthreads();
    }
    if (tid == 0) s_mx = red[0];
    __syncthreads();
    const float mx = s_mx;

    float ls = 0.f;
    for (int d = tid; d < DD; d += 256) ls += expf(xa[d] - mx);
    red[tid] = ls; __syncthreads();
    for (int off = 128; off > 0; off >>= 1) {
        if (tid < off) red[tid] += red[tid + off];
        __syncthreads();
    }
    if (tid == 0) s_sum = red[0];
    __syncthreads();
    const float denom_sm = s_sum;
    __syncthreads();

    for (int d = tid; d < DD; d += 256) {
        int src = d + sh;
        float xo = (src >= 0 && src < DD) ? xr[src] : 0.f;
        float attn = expf(xa[d] - mx) / denom_sm;
        xa[d] = xo * attn;          // x_attn
    }
    __syncthreads();

    // ---- x_ele[j] = x_attn[j + (D-1) - theta] = xa[j - sh] ----
    for (int j = tid; j < DD; j += 256) {
        int s2 = j - sh;
        xe[j] = (s2 >= 0 && s2 < DD) ? xa[s2] : 0.f;
    }
    __syncthreads();

    // ---- h = x_ele @ W_enc + b_enc ----
    for (int h0 = tid; h0 < HD; h0 += 256) {
        float acc = 0.f;
        const float* wc = Wenc + h0;
        for (int j = 0; j < DD; ++j) acc += xe[j] * wc[j * HD];
        acc += benc[h0];
        sv[h0] = acc; si[h0] = h0;
    }
    __syncthreads();

    // ---- bitonic sort descending by value, ties -> smaller index first ----
    for (int k = 2; k <= HD; k <<= 1) {
        for (int j = k >> 1; j > 0; j >>= 1) {
            for (int i = tid; i < HD; i += 256) {
                int ixj = i ^ j;
                if (ixj > i) {
                    float v1 = sv[i], v2 = sv[ixj];
                    int   i1 = si[i], i2 = si[ixj];
                    bool before = (v1 > v2) || (v1 == v2 && i1 < i2);
                    bool up = ((i & k) == 0);
                    if (up ? !before : before) {
                        sv[i] = v2; sv[ixj] = v1;
                        si[i] = i2; si[ixj] = i1;
                    }
                }
            }
            __syncthreads();
        }
    }

    // ---- 4 decode iterations: out_k = sum over rank block (with >1e-10 cutoff for k>0) ----
    for (int k = 0; k < NITER; ++k) {
        float lsum = 0.f;
        for (int d = tid; d < DD; d += 256) {
            float acc = bdec[d];
            for (int r = k * CD; r < k * CD + CD; ++r) {
                float v = sv[r];
                if (k > 0 && !(v > 1e-10f)) break;   // sorted desc -> uniform break
                acc += v * Wdec[si[r] * DD + d];
            }
            out_xdis[((size_t)k * NROWS + row) * DD + d] = acc;
            float e = acc - xr[d];
            if (yr[d] != 0.f) lsum += e * e;
        }
        red[tid] = lsum; __syncthreads();
        for (int off = 128; off > 0; off >>= 1) {
            if (tid < off) red[tid] += red[tid + off];
            __syncthreads();
        }
        if (tid == 0) atomicAdd(&loss_acc[k], red[0]);
        __syncthreads();
    }
}

// Count valid (y != 0) elements, divide loss sums in place.
__global__ __launch_bounds__(256) void finalize_kernel(
    const float* __restrict__ y, float* __restrict__ losses)
{
    __shared__ int cnt[256];
    const int tid = threadIdx.x;
    int c = 0;
    for (int i = tid; i < NROWS * DD; i += 256) if (y[i] != 0.f) c++;
    cnt[tid] = c; __syncthreads();
    for (int off = 128; off > 0; off >>= 1) {
        if (tid < off) cnt[tid] += cnt[tid + off];
        __syncthreads();
    }
    if (tid < NITER) losses[tid] = losses[tid] / (float)cnt[0];
}

extern "C" void kernel_launch(void* const* d_in, const int* in_sizes, int n_in,
                              void* d_out, int out_size, void* d_ws, size_t ws_size,
                              hipStream_t stream) {
    const float* x    = (const float*)d_in[0];
    const float* y    = (const float*)d_in[1];
    const float* Wenc = (const float*)d_in[2];
    const float* benc = (const float*)d_in[3];
    const float* Wdec = (const float*)d_in[4];
    const float* bdec = (const float*)d_in[5];

    float* out  = (float*)d_out;
    float* loss = out + (out_size - NITER);   // losses are the last 4 floats

    hipMemsetAsync(loss, 0, NITER * sizeof(float), stream);
    fused_kernel<<<NROWS, 256, 0, stream>>>(x, y, Wenc, benc, Wdec, bdec, out, loss);
    finalize_kernel<<<1, 256, 0, stream>>>(y, loss);
}

// Round 2
// 244.537 us; speedup vs baseline: 1.8774x; 1.8774x over previous
//
#include <hip/hip_runtime.h>
#include <math.h>

#define DD 384
#define HD 1024
#define CD 256
#define NS (2*DD-1)   // 765 shifts
#define NITER 4
#define NROWS 256     // B*T = 2*128
#define TEMPER_F 10.0f
#define EPSF 1e-6f
#define CUTF 1e-10f

// ---------------- prep: per-row theta / attn / x_ele ----------------
__global__ __launch_bounds__(256) void prep_kernel(
    const float* __restrict__ x, const float* __restrict__ y,
    float* __restrict__ xe_out)
{
    const int row = blockIdx.x;
    const int tid = threadIdx.x;

    __shared__ float xr[DD], yr[DD], xa[DD];
    __shared__ float red[256];
    __shared__ int   redi[256];
    __shared__ float s_qn, s_dn, s_mx, s_sum;
    __shared__ int   s_theta;

    const float* xrow = x + row * DD;
    const float* yrow = y + row * DD;
    for (int i = tid; i < DD; i += 256) { xr[i] = xrow[i]; yr[i] = yrow[i]; }
    __syncthreads();

    // qn = ||y_row||
    float p = 0.f;
    for (int i = tid; i < DD; i += 256) p += yr[i] * yr[i];
    red[tid] = p; __syncthreads();
    for (int off = 128; off > 0; off >>= 1) {
        if (tid < off) red[tid] += red[tid + off];
        __syncthreads();
    }
    if (tid == 0) s_qn = sqrtf(red[0]);
    __syncthreads();
    const float qn = s_qn;

    // sim(s) argmax (first-max tie-break)
    float bv = -INFINITY; int bs = 0;
    for (int s = tid; s < NS; s += 256) {
        int lo = s - (DD - 1); if (lo < 0) lo = 0;
        int hi = s + 1;        if (hi > DD) hi = DD;
        const int off = (DD - 1) - s;
        float dot = 0.f, nrm = 0.f;
        for (int idx = lo; idx < hi; ++idx) {
            float xv = xr[idx];
            dot += xv * yr[idx + off];
            nrm += xv * xv;
        }
        float sim = dot / (qn * sqrtf(nrm) + EPSF);
        if (sim > bv) { bv = sim; bs = s; }
    }
    red[tid] = bv; redi[tid] = bs; __syncthreads();
    for (int off = 128; off > 0; off >>= 1) {
        if (tid < off) {
            float v2 = red[tid + off]; int i2 = redi[tid + off];
            if (v2 > red[tid] || (v2 == red[tid] && i2 < redi[tid])) {
                red[tid] = v2; redi[tid] = i2;
            }
        }
        __syncthreads();
    }
    if (tid == 0) s_theta = redi[0];
    __syncthreads();
    const int theta = s_theta;
    const int sh = theta - (DD - 1);   // x_opt[j] = xr[j + sh]

    // dn = ||x_opt|| * qn + EPS
    p = 0.f;
    for (int d = tid; d < DD; d += 256) {
        int src = d + sh;
        if (src >= 0 && src < DD) { float v = xr[src]; p += v * v; }
    }
    red[tid] = p; __syncthreads();
    for (int off = 128; off > 0; off >>= 1) {
        if (tid < off) red[tid] += red[tid + off];
        __syncthreads();
    }
    if (tid == 0) s_dn = sqrtf(red[0]) * qn + EPSF;
    __syncthreads();
    const float dn = s_dn;

    // softmax((x_opt*y/dn)/T); x_attn = x_opt * attn
    float lm = -INFINITY;
    for (int d = tid; d < DD; d += 256) {
        int src = d + sh;
        float xo = (src >= 0 && src < DD) ? xr[src] : 0.f;
        float z = (xo * yr[d] / dn) / TEMPER_F;
        xa[d] = z;
        if (z > lm) lm = z;
    }
    red[tid] = lm; __syncthreads();
    for (int off = 128; off > 0; off >>= 1) {
        if (tid < off) { float v2 = red[tid + off]; if (v2 > red[tid]) red[tid] = v2; }
        __syncthreads();
    }
    if (tid == 0) s_mx = red[0];
    __syncthreads();
    const float mx = s_mx;

    float ls = 0.f;
    for (int d = tid; d < DD; d += 256) ls += expf(xa[d] - mx);
    red[tid] = ls; __syncthreads();
    for (int off = 128; off > 0; off >>= 1) {
        if (tid < off) red[tid] += red[tid + off];
        __syncthreads();
    }
    if (tid == 0) s_sum = red[0];
    __syncthreads();
    const float denom_sm = s_sum;
    __syncthreads();

    for (int d = tid; d < DD; d += 256) {
        int src = d + sh;
        float xo = (src >= 0 && src < DD) ? xr[src] : 0.f;
        float attn = expf(xa[d] - mx) / denom_sm;
        xa[d] = xo * attn;          // x_attn
    }
    __syncthreads();

    // x_ele[j] = x_attn[j - sh]
    for (int j = tid; j < DD; j += 256) {
        int s2 = j - sh;
        xe_out[row * DD + j] = (s2 >= 0 && s2 < DD) ? xa[s2] : 0.f;
    }
}

// ---------------- encoder: h = xe @ W_enc + b_enc ----------------
// grid = NROWS * (HD/256); block handles one row x 256 h-columns
__global__ __launch_bounds__(256) void encoder_kernel(
    const float* __restrict__ xe, const float* __restrict__ Wenc,
    const float* __restrict__ benc, float* __restrict__ h)
{
    const int row = blockIdx.x >> 2;
    const int h0  = ((blockIdx.x & 3) << 8) + threadIdx.x;
    __shared__ float sxe[DD];
    for (int i = threadIdx.x; i < DD; i += 256) sxe[i] = xe[row * DD + i];
    __syncthreads();
    float acc = benc[h0];
    const float* wc = Wenc + h0;
#pragma unroll 8
    for (int j = 0; j < DD; ++j) acc += sxe[j] * wc[(size_t)j * HD];
    h[row * HD + h0] = acc;
}

// ---------------- sort: bitonic desc per row + active counts ----------------
__global__ __launch_bounds__(256) void sort_kernel(
    const float* __restrict__ h, float* __restrict__ svs,
    int* __restrict__ sis, int* __restrict__ counts)
{
    const int row = blockIdx.x;
    const int tid = threadIdx.x;
    __shared__ float sv[HD];
    __shared__ int   si[HD];
    __shared__ int   cnt[NITER];

    for (int i = tid; i < HD; i += 256) { sv[i] = h[row * HD + i]; si[i] = i; }
    if (tid < NITER) cnt[tid] = (tid == 0) ? CD : 0;
    __syncthreads();

    for (int k = 2; k <= HD; k <<= 1) {
        for (int j = k >> 1; j > 0; j >>= 1) {
            for (int i = tid; i < HD; i += 256) {
                int ixj = i ^ j;
                if (ixj > i) {
                    float v1 = sv[i], v2 = sv[ixj];
                    int   i1 = si[i], i2 = si[ixj];
                    bool before = (v1 > v2) || (v1 == v2 && i1 < i2);
                    bool up = ((i & k) == 0);
                    if (up ? !before : before) {
                        sv[i] = v2; sv[ixj] = v1;
                        si[i] = i2; si[ixj] = i1;
                    }
                }
            }
            __syncthreads();
        }
    }

    // active counts for k>=1 (strictly > 1e-10)
    for (int k = 1; k < NITER; ++k)
        if (sv[k * CD + tid] > CUTF) atomicAdd(&cnt[k], 1);
    for (int i = tid; i < HD; i += 256) {
        svs[row * HD + i] = sv[i];
        sis[row * HD + i] = si[i];
    }
    __syncthreads();
    if (tid < NITER) counts[row * NITER + tid] = cnt[tid];
}

// ---------------- decode: out_k = bdec + sum v*Wdec[idx] + loss ----------------
// grid = NROWS * NITER; 384 threads, one d-column each
__global__ __launch_bounds__(384) void decode_kernel(
    const float* __restrict__ svs, const int* __restrict__ sis,
    const int* __restrict__ counts,
    const float* __restrict__ Wdec, const float* __restrict__ bdec,
    const float* __restrict__ x, const float* __restrict__ y,
    float* __restrict__ out_xdis, float* __restrict__ loss_acc)
{
    const int row = blockIdx.x >> 2;
    const int k   = blockIdx.x & 3;
    const int tid = threadIdx.x;   // d

    __shared__ float v[CD];
    __shared__ int   id[CD];
    __shared__ float red[384];

    if (tid < CD) {
        v[tid]  = svs[row * HD + k * CD + tid];
        id[tid] = sis[row * HD + k * CD + tid] * DD;
    }
    __syncthreads();
    const int n = counts[row * NITER + k];

    float acc = bdec[tid];
    int r = 0;
    for (; r + 4 <= n; r += 4) {
        float v0 = v[r], v1 = v[r+1], v2 = v[r+2], v3 = v[r+3];
        int   i0 = id[r], i1 = id[r+1], i2 = id[r+2], i3 = id[r+3];
        acc += v0 * Wdec[i0 + tid];
        acc += v1 * Wdec[i1 + tid];
        acc += v2 * Wdec[i2 + tid];
        acc += v3 * Wdec[i3 + tid];
    }
    for (; r < n; ++r) acc += v[r] * Wdec[id[r] + tid];

    out_xdis[((size_t)k * NROWS + row) * DD + tid] = acc;
    float e = acc - x[row * DD + tid];
    float l = (y[row * DD + tid] != 0.f) ? e * e : 0.f;

    red[tid] = l; __syncthreads();
    if (tid < 128) red[tid] += red[tid + 256];
    __syncthreads();
    for (int off = 128; off > 0; off >>= 1) {
        if (tid < off && tid + off < 256) red[tid] += red[tid + off];
        __syncthreads();
    }
    if (tid == 0) atomicAdd(&loss_acc[k], red[0]);
}

// ---------------- finalize: divide losses by count(y != 0) ----------------
__global__ __launch_bounds__(256) void finalize_kernel(
    const float* __restrict__ y, float* __restrict__ losses)
{
    __shared__ int cnt[256];
    const int tid = threadIdx.x;
    int c = 0;
    for (int i = tid; i < NROWS * DD; i += 256) if (y[i] != 0.f) c++;
    cnt[tid] = c; __syncthreads();
    for (int off = 128; off > 0; off >>= 1) {
        if (tid < off) cnt[tid] += cnt[tid + off];
        __syncthreads();
    }
    if (tid < NITER) losses[tid] = losses[tid] / (float)cnt[0];
}

extern "C" void kernel_launch(void* const* d_in, const int* in_sizes, int n_in,
                              void* d_out, int out_size, void* d_ws, size_t ws_size,
                              hipStream_t stream) {
    const float* x    = (const float*)d_in[0];
    const float* y    = (const float*)d_in[1];
    const float* Wenc = (const float*)d_in[2];
    const float* benc = (const float*)d_in[3];
    const float* Wdec = (const float*)d_in[4];
    const float* bdec = (const float*)d_in[5];

    float* out  = (float*)d_out;
    float* loss = out + (out_size - NITER);

    // workspace layout (~3.5 MB)
    float* xe     = (float*)d_ws;
    float* h      = xe + (size_t)NROWS * DD;
    float* svs    = h + (size_t)NROWS * HD;
    int*   sis    = (int*)(svs + (size_t)NROWS * HD);
    int*   counts = sis + (size_t)NROWS * HD;

    hipMemsetAsync(loss, 0, NITER * sizeof(float), stream);
    prep_kernel<<<NROWS, 256, 0, stream>>>(x, y, xe);
    encoder_kernel<<<NROWS * (HD / 256), 256, 0, stream>>>(xe, Wenc, benc, h);
    sort_kernel<<<NROWS, 256, 0, stream>>>(h, svs, sis, counts);
    decode_kernel<<<NROWS * NITER, 384, 0, stream>>>(svs, sis, counts, Wdec, bdec,
                                                     x, y, out, loss);
    finalize_kernel<<<1, 256, 0, stream>>>(y, loss);
}

// Round 3
// 146.237 us; speedup vs baseline: 3.1393x; 1.6722x over previous
//
#include <hip/hip_runtime.h>
#include <math.h>

#define DD 384
#define HD 1024
#define CD 256
#define NS 765        // 2*DD-1 shifts
#define NITER 4
#define NROWS 256     // B*T
#define TEMPER_F 10.0f
#define EPSF 1e-6f
#define CUTF 1e-10f
#define XSTR 1156     // padded stride: 1156 % 32 == 4 -> no 4-way bank conflict

// ---------------- prep: per-row theta / attn / x_ele + y-count ----------------
// 384 threads = 6 waves; one d-column per thread.
__global__ __launch_bounds__(384) void prep_kernel(
    const float* __restrict__ x, const float* __restrict__ y,
    float* __restrict__ xe_out, int* __restrict__ ycount)
{
    const int row  = blockIdx.x;
    const int tid  = threadIdx.x;
    const int lane = tid & 63;
    const int wid  = tid >> 6;

    // 4 shifted copies: xp[r][i] = xfull(i + r), xfull(t) = x[t-383] if t in [383,767) else 0
    __shared__ float xp[4][XSTR];
    __shared__ float yr[DD];
    __shared__ float xa[DD];
    __shared__ float wred[8];
    __shared__ int   wredi[8];
    __shared__ float s_qn, s_dn, s_mx, s_sum;
    __shared__ int   s_theta;

    const float* xrow = x + row * DD;
    const float* yrow = y + row * DD;

    for (int i = tid; i < XSTR; i += 384) {
#pragma unroll
        for (int r = 0; r < 4; ++r) {
            int t = i + r;
            xp[r][i] = (t >= DD - 1 && t < 2 * DD - 1) ? xrow[t - (DD - 1)] : 0.f;
        }
    }
    yr[tid] = yrow[tid];
    __syncthreads();

    // ---- qn = ||y|| ----
    {
        float p = yr[tid] * yr[tid];
        for (int o = 32; o > 0; o >>= 1) p += __shfl_xor(p, o, 64);
        if (lane == 0) wred[wid] = p;
        __syncthreads();
        if (tid == 0) {
            float s = 0.f;
            for (int w = 0; w < 6; ++w) s += wred[w];
            s_qn = sqrtf(s);
        }
        __syncthreads();
    }
    const float qn = s_qn;

    // ---- sim(s) over uniform padded windows; 2 shifts per thread ----
    const int s1 = tid, s2 = tid + 384;     // same (s & 3) residue
    const int r4 = tid & 3;
    const float* xps = xp[r4];
    const int a1 = s1 & ~3;                 // 16B-aligned base within copy r4
    const int a2 = a1 + 384;
    float dot1 = 0.f, nrm1 = 0.f, dot2 = 0.f, nrm2 = 0.f;
#pragma unroll 4
    for (int j = 0; j < DD; j += 4) {
        float4 yv  = *(const float4*)&yr[j];        // wave-broadcast
        float4 xv1 = *(const float4*)&xps[a1 + j];  // aligned ds_read_b128
        float4 xv2 = *(const float4*)&xps[a2 + j];
        dot1 += xv1.x * yv.x; nrm1 += xv1.x * xv1.x;
        dot1 += xv1.y * yv.y; nrm1 += xv1.y * xv1.y;
        dot1 += xv1.z * yv.z; nrm1 += xv1.z * xv1.z;
        dot1 += xv1.w * yv.w; nrm1 += xv1.w * xv1.w;
        dot2 += xv2.x * yv.x; nrm2 += xv2.x * xv2.x;
        dot2 += xv2.y * yv.y; nrm2 += xv2.y * xv2.y;
        dot2 += xv2.z * yv.z; nrm2 += xv2.z * xv2.z;
        dot2 += xv2.w * yv.w; nrm2 += xv2.w * xv2.w;
    }
    float sim1 = dot1 / (qn * sqrtf(nrm1) + EPSF);
    float sim2 = dot2 / (qn * sqrtf(nrm2) + EPSF);
    float bv = sim1; int bs = s1;
    if (s2 < NS && sim2 > bv) { bv = sim2; bs = s2; }
    // wave argmax (ties -> smaller s)
    for (int o = 32; o > 0; o >>= 1) {
        float v2 = __shfl_xor(bv, o, 64);
        int   i2 = __shfl_xor(bs, o, 64);
        if (v2 > bv || (v2 == bv && i2 < bs)) { bv = v2; bs = i2; }
    }
    if (lane == 0) { wred[wid] = bv; wredi[wid] = bs; }
    __syncthreads();
    if (tid == 0) {
        float v = wred[0]; int b = wredi[0];
        for (int w = 1; w < 6; ++w)
            if (wred[w] > v || (wred[w] == v && wredi[w] < b)) { v = wred[w]; b = wredi[w]; }
        s_theta = b;
    }
    __syncthreads();
    const int theta = s_theta;
    const int tr = theta & 3, ta = theta & ~3;
    const float xo = xp[tr][ta + tid];      // x_opt[tid] = xfull(theta + tid)

    // ---- dn = ||x_opt|| * qn + EPS ----
    {
        float p = xo * xo;
        for (int o = 32; o > 0; o >>= 1) p += __shfl_xor(p, o, 64);
        if (lane == 0) wred[wid] = p;
        __syncthreads();
        if (tid == 0) {
            float s = 0.f;
            for (int w = 0; w < 6; ++w) s += wred[w];
            s_dn = sqrtf(s) * qn + EPSF;
        }
        __syncthreads();
    }
    const float dn = s_dn;

    // ---- softmax((x_opt*y/dn)/T); x_attn = x_opt * attn ----
    const float z = (xo * yr[tid] / dn) / TEMPER_F;
    {
        float m = z;
        for (int o = 32; o > 0; o >>= 1) { float w = __shfl_xor(m, o, 64); if (w > m) m = w; }
        if (lane == 0) wred[wid] = m;
        __syncthreads();
        if (tid == 0) {
            float mm = wred[0];
            for (int w = 1; w < 6; ++w) if (wred[w] > mm) mm = wred[w];
            s_mx = mm;
        }
        __syncthreads();
    }
    const float ez = expf(z - s_mx);
    {
        float p = ez;
        for (int o = 32; o > 0; o >>= 1) p += __shfl_xor(p, o, 64);
        if (lane == 0) wred[wid] = p;
        __syncthreads();
        if (tid == 0) {
            float s = 0.f;
            for (int w = 0; w < 6; ++w) s += wred[w];
            s_sum = s;
        }
        __syncthreads();
    }
    xa[tid] = xo * (ez / s_sum);            // x_attn
    __syncthreads();

    // ---- x_ele[j] = x_attn[j - sh], sh = theta - (DD-1) ----
    const int sh = theta - (DD - 1);
    const int sj = tid - sh;
    xe_out[row * DD + tid] = (sj >= 0 && sj < DD) ? xa[sj] : 0.f;

    // ---- y-count contribution (one atomic per block) ----
    int c = (yr[tid] != 0.f) ? 1 : 0;
    for (int o = 32; o > 0; o >>= 1) c += __shfl_xor(c, o, 64);
    if (lane == 0) wredi[wid] = c;
    __syncthreads();
    if (tid == 0) {
        int s = 0;
        for (int w = 0; w < 6; ++w) s += wredi[w];
        atomicAdd(ycount, s);
    }
}

// ---------------- encoder: h = xe @ W_enc + b_enc ----------------
__global__ __launch_bounds__(256) void encoder_kernel(
    const float* __restrict__ xe, const float* __restrict__ Wenc,
    const float* __restrict__ benc, float* __restrict__ h)
{
    const int row = blockIdx.x >> 2;
    const int h0  = ((blockIdx.x & 3) << 8) + threadIdx.x;
    __shared__ float sxe[DD];
    for (int i = threadIdx.x; i < DD; i += 256) sxe[i] = xe[row * DD + i];
    __syncthreads();
    float acc = benc[h0];
    const float* wc = Wenc + h0;
#pragma unroll 8
    for (int j = 0; j < DD; ++j) acc += sxe[j] * wc[(size_t)j * HD];
    h[row * HD + h0] = acc;
}

// ---------------- sort: bitonic desc per row + active counts ----------------
// 512 threads: exactly one compare per thread per round.
__global__ __launch_bounds__(512) void sort_kernel(
    const float* __restrict__ h, float* __restrict__ svs,
    int* __restrict__ sis, int* __restrict__ counts)
{
    const int row = blockIdx.x;
    const int tid = threadIdx.x;
    __shared__ float sv[HD];
    __shared__ int   si[HD];
    __shared__ int   cnt[NITER];

    sv[tid]       = h[row * HD + tid];       si[tid]       = tid;
    sv[tid + 512] = h[row * HD + tid + 512]; si[tid + 512] = tid + 512;
    if (tid < NITER) cnt[tid] = (tid == 0) ? CD : 0;
    __syncthreads();

    for (int k = 2; k <= HD; k <<= 1) {
        for (int j = k >> 1; j > 0; j >>= 1) {
            const int low = tid & (j - 1);
            const int i   = ((tid - low) << 1) + low;   // bit j clear
            const int p   = i + j;
            const bool up = ((i & k) == 0);
            float v1 = sv[i], v2 = sv[p];
            int   i1 = si[i], i2 = si[p];
            bool before = (v1 > v2) || (v1 == v2 && i1 < i2);
            if (up ? !before : before) {
                sv[i] = v2; sv[p] = v1;
                si[i] = i2; si[p] = i1;
            }
            __syncthreads();
        }
    }

    // active counts for blocks k>=1 (strictly > 1e-10); entries 256..1023
    {
        int i1x = CD + tid;                  // 256..767
        if (sv[i1x] > CUTF) atomicAdd(&cnt[i1x >> 8], 1);
        if (tid < 256 && sv[768 + tid] > CUTF) atomicAdd(&cnt[3], 1);
    }
    svs[row * HD + tid]       = sv[tid];
    svs[row * HD + tid + 512] = sv[tid + 512];
    sis[row * HD + tid]       = si[tid];
    sis[row * HD + tid + 512] = si[tid + 512];
    __syncthreads();
    if (tid < NITER) counts[row * NITER + tid] = cnt[tid];
}

// ---------------- decode: out_k = bdec + sum v*Wdec[idx] + loss ----------------
__global__ __launch_bounds__(384) void decode_kernel(
    const float* __restrict__ svs, const int* __restrict__ sis,
    const int* __restrict__ counts,
    const float* __restrict__ Wdec, const float* __restrict__ bdec,
    const float* __restrict__ x, const float* __restrict__ y,
    float* __restrict__ out_xdis, float* __restrict__ loss_acc)
{
    const int row  = blockIdx.x >> 2;
    const int k    = blockIdx.x & 3;
    const int tid  = threadIdx.x;   // d
    const int lane = tid & 63;
    const int wid  = tid >> 6;

    __shared__ float v[CD];
    __shared__ int   id[CD];
    __shared__ float wred[8];

    if (tid < CD) {
        v[tid]  = svs[row * HD + k * CD + tid];
        id[tid] = sis[row * HD + k * CD + tid] * DD;
    }
    __syncthreads();
    const int n = counts[row * NITER + k];

    float acc = bdec[tid];
    int r = 0;
    for (; r + 8 <= n; r += 8) {
#pragma unroll
        for (int u = 0; u < 8; ++u)
            acc += v[r + u] * Wdec[id[r + u] + tid];
    }
    for (; r < n; ++r) acc += v[r] * Wdec[id[r] + tid];

    out_xdis[((size_t)k * NROWS + row) * DD + tid] = acc;
    float e = acc - x[row * DD + tid];
    float l = (y[row * DD + tid] != 0.f) ? e * e : 0.f;

    for (int o = 32; o > 0; o >>= 1) l += __shfl_xor(l, o, 64);
    if (lane == 0) wred[wid] = l;
    __syncthreads();
    if (tid == 0) {
        float s = 0.f;
        for (int w = 0; w < 6; ++w) s += wred[w];
        atomicAdd(&loss_acc[k], s);
    }
}

// ---------------- finalize: divide losses by precomputed count ----------------
__global__ __launch_bounds__(64) void div_kernel(
    float* __restrict__ losses, const int* __restrict__ ycount)
{
    const int t = threadIdx.x;
    if (t < NITER) losses[t] = losses[t] / (float)(*ycount);
}

extern "C" void kernel_launch(void* const* d_in, const int* in_sizes, int n_in,
                              void* d_out, int out_size, void* d_ws, size_t ws_size,
                              hipStream_t stream) {
    const float* x    = (const float*)d_in[0];
    const float* y    = (const float*)d_in[1];
    const float* Wenc = (const float*)d_in[2];
    const float* benc = (const float*)d_in[3];
    const float* Wdec = (const float*)d_in[4];
    const float* bdec = (const float*)d_in[5];

    float* out  = (float*)d_out;
    float* loss = out + (out_size - NITER);

    // workspace layout
    float* xe     = (float*)d_ws;
    float* h      = xe + (size_t)NROWS * DD;
    float* svs    = h + (size_t)NROWS * HD;
    int*   sis    = (int*)(svs + (size_t)NROWS * HD);
    int*   counts = sis + (size_t)NROWS * HD;
    int*   ycount = counts + NROWS * NITER;

    hipMemsetAsync(loss, 0, NITER * sizeof(float), stream);
    hipMemsetAsync(ycount, 0, sizeof(int), stream);
    prep_kernel<<<NROWS, 384, 0, stream>>>(x, y, xe, ycount);
    encoder_kernel<<<NROWS * (HD / 256), 256, 0, stream>>>(xe, Wenc, benc, h);
    sort_kernel<<<NROWS, 512, 0, stream>>>(h, svs, sis, counts);
    decode_kernel<<<NROWS * NITER, 384, 0, stream>>>(svs, sis, counts, Wdec, bdec,
                                                     x, y, out, loss);
    div_kernel<<<1, 64, 0, stream>>>(loss, ycount);
}

// Round 4
// 123.878 us; speedup vs baseline: 3.7060x; 1.1805x over previous
//
#include <hip/hip_runtime.h>
#include <math.h>

#define DD 384
#define HD 1024
#define CD 256
#define NS 765        // 2*DD-1 shifts
#define NITER 4
#define NROWS 256     // B*T
#define TEMPER_F 10.0f
#define EPSF 1e-6f
#define CUTF 1e-10f
#define XSTR 1156     // padded stride; 1156 % 32 == 4 -> staggered banks

typedef unsigned long long u64;
typedef unsigned int u32;

// monotone float->uint (ascending)
__device__ __forceinline__ u32 flipf(float f) {
    u32 u = __float_as_uint(f);
    return u ^ ((u32)((int)u >> 31) | 0x80000000u);
}
// inverse, where s = ~flip(v)
__device__ __forceinline__ float unflipf(u32 s) {
    u32 fl = ~s;
    u32 u = (fl & 0x80000000u) ? (fl ^ 0x80000000u) : ~fl;
    return __uint_as_float(u);
}

// One block per row: prep -> encoder -> sort(u64 keys) -> decode.
__global__ __launch_bounds__(512) void fused_kernel(
    const float* __restrict__ x, const float* __restrict__ y,
    const float* __restrict__ Wenc, const float* __restrict__ benc,
    const float* __restrict__ Wdec, const float* __restrict__ bdec,
    float* __restrict__ out_xdis, float* __restrict__ lossp,
    int* __restrict__ ycnt)
{
    const int row  = blockIdx.x;
    const int tid  = threadIdx.x;
    const int lane = tid & 63;
    const int wid  = tid >> 6;

    __shared__ float xp[4][XSTR];   // 4 shifted copies of padded x
    __shared__ float yr[DD];
    __shared__ float xa[DD];
    __shared__ float xe_s[DD];
    __shared__ u64   skey[HD];      // sort keys: (~flip(h))<<32 | idx
    __shared__ uint2 dec2[HD];      // decoded: {bits(v), idx*DD}
    __shared__ float wred[8];
    __shared__ int   wredi[8];
    __shared__ float s_sc[4];       // qn, dn, mx, sum
    __shared__ int   s_theta, s_fb;
    __shared__ float loss4[NITER];

    const float* xrow = x + row * DD;
    const float* yrow = y + row * DD;

    // xp[r][i] = xfull(i+r); xfull(t) = x[t-383] for t in [383,767), else 0
    for (int i = tid; i < XSTR; i += 512) {
#pragma unroll
        for (int r = 0; r < 4; ++r) {
            int t = i + r;
            xp[r][i] = (t >= DD - 1 && t < 2 * DD - 1) ? xrow[t - (DD - 1)] : 0.f;
        }
    }
    if (tid < DD) yr[tid] = yrow[tid];
    __syncthreads();

    // ---- qn = ||y|| (waves 0..5) ----
    if (tid < DD) {
        float p = yr[tid] * yr[tid];
        for (int o = 32; o; o >>= 1) p += __shfl_xor(p, o, 64);
        if (lane == 0) wred[wid] = p;
    }
    __syncthreads();
    if (tid == 0) {
        float s = 0.f;
        for (int w = 0; w < 6; ++w) s += wred[w];
        s_sc[0] = sqrtf(s);
    }
    __syncthreads();
    const float qn = s_sc[0];

    // ---- sim(s) argmax: thread -> shifts tid and tid+512 ----
    const float* xps = xp[tid & 3];
    const int a1 = tid & ~3;
    float bv; int bs;
    if (tid < NS - 512) {          // two shifts
        float dot1 = 0.f, nrm1 = 0.f, dot2 = 0.f, nrm2 = 0.f;
#pragma unroll 4
        for (int j = 0; j < DD; j += 4) {
            float4 yv = *(const float4*)&yr[j];
            float4 x1 = *(const float4*)&xps[a1 + j];
            float4 x2 = *(const float4*)&xps[a1 + 512 + j];
            dot1 += x1.x * yv.x; nrm1 += x1.x * x1.x;
            dot1 += x1.y * yv.y; nrm1 += x1.y * x1.y;
            dot1 += x1.z * yv.z; nrm1 += x1.z * x1.z;
            dot1 += x1.w * yv.w; nrm1 += x1.w * x1.w;
            dot2 += x2.x * yv.x; nrm2 += x2.x * x2.x;
            dot2 += x2.y * yv.y; nrm2 += x2.y * x2.y;
            dot2 += x2.z * yv.z; nrm2 += x2.z * x2.z;
            dot2 += x2.w * yv.w; nrm2 += x2.w * x2.w;
        }
        float sim1 = dot1 / (qn * sqrtf(nrm1) + EPSF);
        float sim2 = dot2 / (qn * sqrtf(nrm2) + EPSF);
        bv = sim1; bs = tid;
        if (sim2 > bv) { bv = sim2; bs = tid + 512; }   // strict: keeps smaller s
    } else {                       // one shift
        float dot1 = 0.f, nrm1 = 0.f;
#pragma unroll 4
        for (int j = 0; j < DD; j += 4) {
            float4 yv = *(const float4*)&yr[j];
            float4 x1 = *(const float4*)&xps[a1 + j];
            dot1 += x1.x * yv.x; nrm1 += x1.x * x1.x;
            dot1 += x1.y * yv.y; nrm1 += x1.y * x1.y;
            dot1 += x1.z * yv.z; nrm1 += x1.z * x1.z;
            dot1 += x1.w * yv.w; nrm1 += x1.w * x1.w;
        }
        bv = dot1 / (qn * sqrtf(nrm1) + EPSF);
        bs = tid;
    }
    for (int o = 32; o; o >>= 1) {
        float v2 = __shfl_xor(bv, o, 64);
        int   i2 = __shfl_xor(bs, o, 64);
        if (v2 > bv || (v2 == bv && i2 < bs)) { bv = v2; bs = i2; }
    }
    if (lane == 0) { wred[wid] = bv; wredi[wid] = bs; }
    __syncthreads();
    if (tid == 0) {
        float v = wred[0]; int b = wredi[0];
        for (int w = 1; w < 8; ++w)
            if (wred[w] > v || (wred[w] == v && wredi[w] < b)) { v = wred[w]; b = wredi[w]; }
        s_theta = b;
    }
    __syncthreads();
    const int theta = s_theta;

    // ---- x_opt, dn, softmax, x_attn (threads < 384) ----
    float xo = 0.f;
    if (tid < DD) {
        xo = xp[theta & 3][(theta & ~3) + tid];
        float p = xo * xo;
        for (int o = 32; o; o >>= 1) p += __shfl_xor(p, o, 64);
        if (lane == 0) wred[wid] = p;
    }
    __syncthreads();
    if (tid == 0) {
        float s = 0.f;
        for (int w = 0; w < 6; ++w) s += wred[w];
        s_sc[1] = sqrtf(s) * qn + EPSF;
    }
    __syncthreads();
    float z = 0.f;
    if (tid < DD) {
        z = (xo * yr[tid] / s_sc[1]) / TEMPER_F;
        float m = z;
        for (int o = 32; o; o >>= 1) { float w2 = __shfl_xor(m, o, 64); if (w2 > m) m = w2; }
        if (lane == 0) wred[wid] = m;
    }
    __syncthreads();
    if (tid == 0) {
        float m = wred[0];
        for (int w = 1; w < 6; ++w) if (wred[w] > m) m = wred[w];
        s_sc[2] = m;
    }
    __syncthreads();
    float ez = 0.f;
    if (tid < DD) {
        ez = expf(z - s_sc[2]);
        float p = ez;
        for (int o = 32; o; o >>= 1) p += __shfl_xor(p, o, 64);
        if (lane == 0) wred[wid] = p;
    }
    __syncthreads();
    if (tid == 0) {
        float s = 0.f;
        for (int w = 0; w < 6; ++w) s += wred[w];
        s_sc[3] = s;
    }
    __syncthreads();
    if (tid < DD) {
        xa[tid] = xo * (ez / s_sc[3]);          // x_attn
        int c = (yr[tid] != 0.f) ? 1 : 0;       // y-count, folded in here
        for (int o = 32; o; o >>= 1) c += __shfl_xor(c, o, 64);
        if (lane == 0) wredi[wid] = c;
    }
    __syncthreads();
    if (tid == 0) {
        int s = 0;
        for (int w = 0; w < 6; ++w) s += wredi[w];
        ycnt[row] = s;
    }
    if (tid < DD) {
        int sj = tid - (theta - (DD - 1));
        xe_s[tid] = (sj >= 0 && sj < DD) ? xa[sj] : 0.f;
    }
    __syncthreads();

    // ---- encoder: h[tid], h[tid+512] ----
    float h0 = benc[tid], h1 = benc[tid + 512];
    const float* w0 = Wenc + tid;
#pragma unroll 4
    for (int j = 0; j < DD; j += 4) {
        float4 xv = *(const float4*)&xe_s[j];
        h0 += xv.x * w0[(j + 0) * HD];       h1 += xv.x * w0[(j + 0) * HD + 512];
        h0 += xv.y * w0[(j + 1) * HD];       h1 += xv.y * w0[(j + 1) * HD + 512];
        h0 += xv.z * w0[(j + 2) * HD];       h1 += xv.z * w0[(j + 2) * HD + 512];
        h0 += xv.w * w0[(j + 3) * HD];       h1 += xv.w * w0[(j + 3) * HD + 512];
    }
    skey[tid]       = ((u64)(~flipf(h0)) << 32) | (u32)tid;
    skey[tid + 512] = ((u64)(~flipf(h1)) << 32) | (u32)(tid + 512);
    if (tid == 0) s_fb = HD;
    if (tid < NITER) loss4[tid] = 0.f;
    __syncthreads();

    // ---- bitonic sort ascending on u64 key (== desc value, asc index) ----
    // j<=64 rounds stay inside one wave's 128-elem segment -> wave_barrier only.
    bool prevc = false;
    for (int k = 2; k <= HD; k <<= 1) {
        for (int j = k >> 1; j > 0; j >>= 1) {
            if (j >= 128 || prevc) __syncthreads();
            else __builtin_amdgcn_wave_barrier();
            const int low = tid & (j - 1);
            const int i   = ((tid - low) << 1) + low;
            const int p   = i + j;
            u64 a = skey[i], b = skey[p];
            const bool up = ((i & k) == 0);
            if (up ? (a > b) : (a < b)) { skey[i] = b; skey[p] = a; }
            prevc = (j >= 128);
        }
    }
    __syncthreads();

    // ---- decode prep: unpack (v, Wdec offset); first pos with v <= CUTF ----
    int fbloc = HD;
#pragma unroll
    for (int u = 0; u < 2; ++u) {
        int pos = tid + u * 512;
        u64 kk = skey[pos];
        float v = unflipf((u32)(kk >> 32));
        u32 idx = (u32)kk;
        dec2[pos] = make_uint2(__float_as_uint(v), idx * DD);
        if (!(v > CUTF) && pos < fbloc) fbloc = pos;
    }
    for (int o = 32; o; o >>= 1) { int t2 = __shfl_xor(fbloc, o, 64); if (t2 < fbloc) fbloc = t2; }
    if (lane == 0) atomicMin(&s_fb, fbloc);
    __syncthreads();
    const int fb = s_fb;

    // ---- decode: 3 outputs per thread; k uniform per wave ----
#pragma unroll
    for (int u = 0; u < 3; ++u) {
        const int gi = u * 512 + tid;
        const int k  = gi / DD;                 // wave-uniform (384|768|1152 are x64)
        const int d  = gi - k * DD;
        int n = (k == 0) ? CD : fb - k * CD;
        if (n < 0) n = 0; if (n > CD) n = CD;
        float acc = bdec[d];
        const float* wd = Wdec + d;
        const int base = k * CD;
        int r = 0;
        for (; r + 8 <= n; r += 8) {
#pragma unroll
            for (int q = 0; q < 8; q += 2) {
                uint4 dv = *(const uint4*)&dec2[base + r + q];   // 2 entries, b128
                acc += __uint_as_float(dv.x) * wd[dv.y];
                acc += __uint_as_float(dv.z) * wd[dv.w];
            }
        }
        for (; r < n; ++r) {
            uint2 dv = dec2[base + r];
            acc += __uint_as_float(dv.x) * wd[dv.y];
        }
        out_xdis[((size_t)k * NROWS + row) * DD + d] = acc;
        float e = acc - xrow[d];
        float l = (yr[d] != 0.f) ? e * e : 0.f;
        for (int o = 32; o; o >>= 1) l += __shfl_xor(l, o, 64);
        if (lane == 0) atomicAdd(&loss4[k], l);
    }
    __syncthreads();
    if (tid < NITER) lossp[row * NITER + tid] = loss4[tid];
}

// ---- finalize: losses[k] = sum_rows lossp / sum_rows ycnt ----
__global__ __launch_bounds__(256) void finalize2(
    const float* __restrict__ lossp, const int* __restrict__ ycnt,
    float* __restrict__ losses)
{
    const int tid = threadIdx.x, lane = tid & 63, w = tid >> 6;
    __shared__ int ctot[4];
    int c = ycnt[tid];
    for (int o = 32; o; o >>= 1) c += __shfl_xor(c, o, 64);
    if (lane == 0) ctot[w] = c;
    __syncthreads();
    const int total = ctot[0] + ctot[1] + ctot[2] + ctot[3];
    // wave w handles loss k=w
    float s = lossp[lane * NITER + w] + lossp[(lane + 64) * NITER + w]
            + lossp[(lane + 128) * NITER + w] + lossp[(lane + 192) * NITER + w];
    for (int o = 32; o; o >>= 1) s += __shfl_xor(s, o, 64);
    if (lane == 0) losses[w] = s / (float)total;
}

extern "C" void kernel_launch(void* const* d_in, const int* in_sizes, int n_in,
                              void* d_out, int out_size, void* d_ws, size_t ws_size,
                              hipStream_t stream) {
    const float* x    = (const float*)d_in[0];
    const float* y    = (const float*)d_in[1];
    const float* Wenc = (const float*)d_in[2];
    const float* benc = (const float*)d_in[3];
    const float* Wdec = (const float*)d_in[4];
    const float* bdec = (const float*)d_in[5];

    float* out  = (float*)d_out;
    float* loss = out + (out_size - NITER);

    float* lossp = (float*)d_ws;                       // 256*4 floats, fully written
    int*   ycnt  = (int*)(lossp + NROWS * NITER);      // 256 ints, fully written

    fused_kernel<<<NROWS, 512, 0, stream>>>(x, y, Wenc, benc, Wdec, bdec,
                                            out, lossp, ycnt);
    finalize2<<<1, 256, 0, stream>>>(lossp, ycnt, loss);
}

// Round 5
// 118.548 us; speedup vs baseline: 3.8726x; 1.0450x over previous
//
#include <hip/hip_runtime.h>
#include <math.h>

#define DD 384
#define HD 1024
#define CD 256
#define NS 765        // 2*DD-1 shifts
#define NITER 4
#define NROWS 256     // B*T
#define TEMPER_F 10.0f
#define EPSF 1e-6f
#define CUTF 1e-10f
#define XPLEN 1152            // padded xfull length (1148 -> 1152 for float4)
#define SKLEN (HD + (HD>>4))  // skewed skey storage (1088)

typedef unsigned long long u64;
typedef unsigned int u32;

// monotone float->uint (ascending)
__device__ __forceinline__ u32 flipf(float f) {
    u32 u = __float_as_uint(f);
    return u ^ ((u32)((int)u >> 31) | 0x80000000u);
}
// inverse, where s = ~flip(v)
__device__ __forceinline__ float unflipf(u32 s) {
    u32 fl = ~s;
    u32 u = (fl & 0x80000000u) ? (fl ^ 0x80000000u) : ~fl;
    return __uint_as_float(u);
}
// bank-skewed LDS index for u64 sort keys: rotate each 16-elem (128B) row
__device__ __forceinline__ int phys(int i) { return i + (i >> 4); }

// One block per row: prep -> encoder -> sort(u64 keys, skewed) -> decode.
__global__ __launch_bounds__(512) void fused_kernel(
    const float* __restrict__ x, const float* __restrict__ y,
    const float* __restrict__ Wenc, const float* __restrict__ benc,
    const float* __restrict__ Wdec, const float* __restrict__ bdec,
    float* __restrict__ out_xdis, float* __restrict__ lossp,
    int* __restrict__ ycnt)
{
    const int row  = blockIdx.x;
    const int tid  = threadIdx.x;
    const int lane = tid & 63;
    const int wid  = tid >> 6;

    __shared__ __align__(16) float xpad[XPLEN];   // xfull(t): x padded both sides
    __shared__ __align__(16) float yr[DD];
    __shared__ float xa[DD];
    __shared__ __align__(16) float xe_s[DD];
    __shared__ __align__(16) float hpart[HD];     // encoder split-K partial
    __shared__ u64   skey[SKLEN];                 // sort keys (skewed storage)
    __shared__ __align__(16) uint2 dec2[HD];      // {bits(v), idx*DD}
    __shared__ float wred[8];
    __shared__ int   wredi[8];
    __shared__ float wredn[8];
    __shared__ float s_sc[4];                     // qn, dn, mx, sum
    __shared__ int   s_theta, s_fb;
    __shared__ float loss4[NITER];

    const float* xrow = x + row * DD;
    const float* yrow = y + row * DD;

    // xfull(t) = x[t-383] for t in [383,767), else 0
    for (int i = tid; i < XPLEN; i += 512)
        xpad[i] = (i >= DD - 1 && i < 2 * DD - 1) ? xrow[i - (DD - 1)] : 0.f;
    if (tid < DD) yr[tid] = yrow[tid];
    __syncthreads();

    // ---- qn = ||y|| ----
    if (tid < DD) {
        float p = yr[tid] * yr[tid];
        for (int o = 32; o; o >>= 1) p += __shfl_xor(p, o, 64);
        if (lane == 0) wred[wid] = p;
    }
    __syncthreads();
    if (tid == 0) {
        float s = 0.f;
        for (int w = 0; w < 6; ++w) s += wred[w];
        s_sc[0] = sqrtf(s);
    }
    __syncthreads();
    const float qn = s_sc[0];

    // ---- sim(s) argmax: threads 0..191, 4 consecutive shifts each,
    //      sliding 8-float register window: 1 new ds_read_b128 per 4-j chunk ----
    float bv = -INFINITY; int bs = 0x7fffffff; float bn = 0.f;
    if (tid < 192) {
        const float4* xp4 = (const float4*)xpad;
        const float4* yp4 = (const float4*)yr;
        float4 A = xp4[tid];                   // xpad[s0 .. s0+3], s0 = 4*tid
        const float f0 = A.x * A.x, f1 = A.y * A.y, f2 = A.z * A.z;
        float d0 = 0.f, d1 = 0.f, d2 = 0.f, d3 = 0.f, n0 = 0.f;
#pragma unroll 4
        for (int jc = 0; jc < 96; ++jc) {
            float4 B = xp4[tid + jc + 1];
            float4 Y = yp4[jc];                // broadcast
            d0 += A.x * Y.x; d0 += A.y * Y.y; d0 += A.z * Y.z; d0 += A.w * Y.w;
            d1 += A.y * Y.x; d1 += A.z * Y.y; d1 += A.w * Y.z; d1 += B.x * Y.w;
            d2 += A.z * Y.x; d2 += A.w * Y.y; d2 += B.x * Y.z; d2 += B.y * Y.w;
            d3 += A.w * Y.x; d3 += B.x * Y.y; d3 += B.y * Y.z; d3 += B.z * Y.w;
            n0 += A.x * A.x; n0 += A.y * A.y; n0 += A.z * A.z; n0 += A.w * A.w;
            A = B;
        }
        // A now = xpad[s0+384 .. s0+387]
        const float n1 = n0 - f0 + A.x * A.x;
        const float n2 = n1 - f1 + A.y * A.y;
        const float n3 = n2 - f2 + A.z * A.z;
        const int s0 = 4 * tid;
        float sim0 = d0 / (qn * sqrtf(n0) + EPSF);
        float sim1 = d1 / (qn * sqrtf(n1) + EPSF);
        float sim2 = d2 / (qn * sqrtf(n2) + EPSF);
        float sim3 = d3 / (qn * sqrtf(n3) + EPSF);
        bv = sim0; bs = s0; bn = n0;
        if (s0 + 1 < NS && sim1 > bv) { bv = sim1; bs = s0 + 1; bn = n1; }
        if (s0 + 2 < NS && sim2 > bv) { bv = sim2; bs = s0 + 2; bn = n2; }
        if (s0 + 3 < NS && sim3 > bv) { bv = sim3; bs = s0 + 3; bn = n3; }
    }
    for (int o = 32; o; o >>= 1) {
        float v2 = __shfl_xor(bv, o, 64);
        int   i2 = __shfl_xor(bs, o, 64);
        float n2 = __shfl_xor(bn, o, 64);
        if (v2 > bv || (v2 == bv && i2 < bs)) { bv = v2; bs = i2; bn = n2; }
    }
    if (lane == 0) { wred[wid] = bv; wredi[wid] = bs; wredn[wid] = bn; }
    __syncthreads();
    if (tid == 0) {
        float v = wred[0]; int b = wredi[0]; float nn = wredn[0];
        for (int w = 1; w < 8; ++w)
            if (wred[w] > v || (wred[w] == v && wredi[w] < b)) {
                v = wred[w]; b = wredi[w]; nn = wredn[w];
            }
        s_theta = b;
        s_sc[1] = sqrtf(nn) * qn + EPSF;      // dn, from carried nrm(theta)
    }
    __syncthreads();
    const int theta = s_theta;
    const float dn = s_sc[1];

    // ---- softmax((x_opt*y/dn)/T); x_attn; y-count ----
    float xo = 0.f, z = 0.f;
    if (tid < DD) {
        xo = xpad[theta + tid];               // x_opt
        z = (xo * yr[tid] / dn) / TEMPER_F;
        float m = z;
        for (int o = 32; o; o >>= 1) { float w2 = __shfl_xor(m, o, 64); if (w2 > m) m = w2; }
        if (lane == 0) wred[wid] = m;
    }
    __syncthreads();
    if (tid == 0) {
        float m = wred[0];
        for (int w = 1; w < 6; ++w) if (wred[w] > m) m = wred[w];
        s_sc[2] = m;
    }
    __syncthreads();
    float ez = 0.f;
    if (tid < DD) {
        ez = expf(z - s_sc[2]);
        float p = ez;
        for (int o = 32; o; o >>= 1) p += __shfl_xor(p, o, 64);
        if (lane == 0) wred[wid] = p;
    }
    __syncthreads();
    if (tid == 0) {
        float s = 0.f;
        for (int w = 0; w < 6; ++w) s += wred[w];
        s_sc[3] = s;
    }
    __syncthreads();
    if (tid < DD) {
        xa[tid] = xo * (ez / s_sc[3]);        // x_attn
        int c = (yr[tid] != 0.f) ? 1 : 0;
        for (int o = 32; o; o >>= 1) c += __shfl_xor(c, o, 64);
        if (lane == 0) wredi[wid] = c;
    }
    __syncthreads();
    if (tid == 0) {
        int s = 0;
        for (int w = 0; w < 6; ++w) s += wredi[w];
        ycnt[row] = s;
    }
    if (tid < DD) {
        int sj = tid - (theta - (DD - 1));
        xe_s[tid] = (sj >= 0 && sj < DD) ? xa[sj] : 0.f;
    }
    __syncthreads();

    // ---- encoder: split-K float4 GEMV. tid<256: j in [0,192); tid>=256: [192,384) ----
    const int c4 = tid & 255;
    const int jh = tid >> 8;
    float4 acc = make_float4(0.f, 0.f, 0.f, 0.f);
    {
        const float* wbase = Wenc + (size_t)(jh * 192) * HD + 4 * c4;
        const float* xb = xe_s + jh * 192;
#pragma unroll 4
        for (int j = 0; j < 192; ++j) {
            float xv = xb[j];                 // broadcast
            float4 w = *(const float4*)(wbase + (size_t)j * HD);
            acc.x += xv * w.x; acc.y += xv * w.y;
            acc.z += xv * w.z; acc.w += xv * w.w;
        }
    }
    if (jh == 1) *(float4*)&hpart[4 * c4] = acc;
    if (tid == 0) s_fb = HD;
    if (tid < NITER) loss4[tid] = 0.f;
    __syncthreads();
    if (jh == 0) {
        float4 hp = *(const float4*)&hpart[4 * c4];
        float4 bb = *(const float4*)&benc[4 * c4];
        float hv0 = acc.x + hp.x + bb.x;
        float hv1 = acc.y + hp.y + bb.y;
        float hv2 = acc.z + hp.z + bb.z;
        float hv3 = acc.w + hp.w + bb.w;
        const int col = 4 * c4;
        skey[phys(col + 0)] = ((u64)(~flipf(hv0)) << 32) | (u32)(col + 0);
        skey[phys(col + 1)] = ((u64)(~flipf(hv1)) << 32) | (u32)(col + 1);
        skey[phys(col + 2)] = ((u64)(~flipf(hv2)) << 32) | (u32)(col + 2);
        skey[phys(col + 3)] = ((u64)(~flipf(hv3)) << 32) | (u32)(col + 3);
    }
    __syncthreads();

    // ---- bitonic sort ascending on u64 key (desc value, asc index), skewed LDS ----
    bool prevc = false;
    for (int k = 2; k <= HD; k <<= 1) {
        for (int j = k >> 1; j > 0; j >>= 1) {
            if (j >= 128 || prevc) __syncthreads();
            else __builtin_amdgcn_wave_barrier();
            const int low = tid & (j - 1);
            const int i   = ((tid - low) << 1) + low;
            const int p   = i + j;
            const int pi = phys(i), pp = phys(p);
            u64 a = skey[pi], b = skey[pp];
            const bool up = ((i & k) == 0);
            if (up ? (a > b) : (a < b)) { skey[pi] = b; skey[pp] = a; }
            prevc = (j >= 128);
        }
    }
    __syncthreads();

    // ---- unpack + first position with v <= CUTF ----
    int fbloc = HD;
#pragma unroll
    for (int u2 = 0; u2 < 2; ++u2) {
        int pos = tid + u2 * 512;
        u64 kk = skey[phys(pos)];
        float v = unflipf((u32)(kk >> 32));
        u32 idx = (u32)kk;
        dec2[pos] = make_uint2(__float_as_uint(v), idx * DD);
        if (!(v > CUTF) && pos < fbloc) fbloc = pos;
    }
    for (int o = 32; o; o >>= 1) { int t2 = __shfl_xor(fbloc, o, 64); if (t2 < fbloc) fbloc = t2; }
    if (lane == 0) atomicMin(&s_fb, fbloc);
    __syncthreads();
    const int fb = s_fb;

    // ---- decode: 4 groups of 128 threads (k wave-uniform), 4 d-cols/thread ----
    {
        const int k  = tid >> 7;
        const int g  = tid & 127;
        const bool active = (g < 96);
        int n = 0;
        if (active) {
            n = (k == 0) ? CD : fb - k * CD;
            if (n < 0) n = 0; if (n > CD) n = CD;
        }
        float4 oacc = make_float4(0.f, 0.f, 0.f, 0.f);
        if (active) oacc = *(const float4*)&bdec[4 * g];
        const float* wd = Wdec + 4 * g;
        const int base = k * CD;
        int r = 0;
        for (; r + 2 <= n; r += 2) {
            uint4 dv = *(const uint4*)&dec2[base + r];    // 2 entries, broadcast b128
            float v0 = __uint_as_float(dv.x);
            float4 w0 = *(const float4*)(wd + dv.y);
            float v1 = __uint_as_float(dv.z);
            float4 w1 = *(const float4*)(wd + dv.w);
            oacc.x += v0 * w0.x; oacc.y += v0 * w0.y;
            oacc.z += v0 * w0.z; oacc.w += v0 * w0.w;
            oacc.x += v1 * w1.x; oacc.y += v1 * w1.y;
            oacc.z += v1 * w1.z; oacc.w += v1 * w1.w;
        }
        if (r < n) {
            uint2 dv = dec2[base + r];
            float v0 = __uint_as_float(dv.x);
            float4 w0 = *(const float4*)(wd + dv.y);
            oacc.x += v0 * w0.x; oacc.y += v0 * w0.y;
            oacc.z += v0 * w0.z; oacc.w += v0 * w0.w;
        }
        float l = 0.f;
        if (active) {
            *(float4*)&out_xdis[((size_t)k * NROWS + row) * DD + 4 * g] = oacc;
            float4 xv = *(const float4*)&xrow[4 * g];
            float4 yv = *(const float4*)&yr[4 * g];
            float e;
            e = oacc.x - xv.x; if (yv.x != 0.f) l += e * e;
            e = oacc.y - xv.y; if (yv.y != 0.f) l += e * e;
            e = oacc.z - xv.z; if (yv.z != 0.f) l += e * e;
            e = oacc.w - xv.w; if (yv.w != 0.f) l += e * e;
        }
        for (int o = 32; o; o >>= 1) l += __shfl_xor(l, o, 64);
        if (lane == 0) atomicAdd(&loss4[k], l);
    }
    __syncthreads();
    if (tid < NITER) lossp[row * NITER + tid] = loss4[tid];
}

// ---- finalize: losses[k] = sum_rows lossp / sum_rows ycnt ----
__global__ __launch_bounds__(256) void finalize2(
    const float* __restrict__ lossp, const int* __restrict__ ycnt,
    float* __restrict__ losses)
{
    const int tid = threadIdx.x, lane = tid & 63, w = tid >> 6;
    __shared__ int ctot[4];
    int c = ycnt[tid];
    for (int o = 32; o; o >>= 1) c += __shfl_xor(c, o, 64);
    if (lane == 0) ctot[w] = c;
    __syncthreads();
    const int total = ctot[0] + ctot[1] + ctot[2] + ctot[3];
    float s = lossp[lane * NITER + w] + lossp[(lane + 64) * NITER + w]
            + lossp[(lane + 128) * NITER + w] + lossp[(lane + 192) * NITER + w];
    for (int o = 32; o; o >>= 1) s += __shfl_xor(s, o, 64);
    if (lane == 0) losses[w] = s / (float)total;
}

extern "C" void kernel_launch(void* const* d_in, const int* in_sizes, int n_in,
                              void* d_out, int out_size, void* d_ws, size_t ws_size,
                              hipStream_t stream) {
    const float* x    = (const float*)d_in[0];
    const float* y    = (const float*)d_in[1];
    const float* Wenc = (const float*)d_in[2];
    const float* benc = (const float*)d_in[3];
    const float* Wdec = (const float*)d_in[4];
    const float* bdec = (const float*)d_in[5];

    float* out  = (float*)d_out;
    float* loss = out + (out_size - NITER);

    float* lossp = (float*)d_ws;                       // 256*4 floats, fully written
    int*   ycnt  = (int*)(lossp + NROWS * NITER);      // 256 ints, fully written

    fused_kernel<<<NROWS, 512, 0, stream>>>(x, y, Wenc, benc, Wdec, bdec,
                                            out, lossp, ycnt);
    finalize2<<<1, 256, 0, stream>>>(lossp, ycnt, loss);
}